// Round 1
// baseline (309.236 us; speedup 1.0000x reference)
//
#include <hip/hip_runtime.h>
#include <math.h>

#define NROWS 65536
#define D 64
#define K 1024
#define TK 64          // codes per LDS buffer
#define KSPLIT 2       // k-range halves per row
#define ROWS_PER_BLOCK 128
#define THREADS 256

// Kernel 0: c[k] = sum_j E[k][j]^2
__global__ void vq_enorm(const float* __restrict__ E, float* __restrict__ c) {
    int k = blockIdx.x * blockDim.x + threadIdx.x;
    if (k >= K) return;
    const float4* ev = (const float4*)(E + (size_t)k * D);
    float s = 0.f;
#pragma unroll
    for (int p = 0; p < D / 4; ++p) {
        float4 v = ev[p];
        s += v.x * v.x + v.y * v.y + v.z * v.z + v.w * v.w;
    }
    c[k] = s;
}

__global__ __launch_bounds__(THREADS) void vq_main(
    const float* __restrict__ X, const float* __restrict__ E,
    const float* __restrict__ C, float* __restrict__ out,
    float* __restrict__ lossp)
{
    __shared__ float sE[KSPLIT * TK * D];   // 32 KB, two contiguous code tiles
    __shared__ float sC[KSPLIT * TK];
    __shared__ float sD[THREADS];
    __shared__ int   sI[THREADS];

    const int t    = threadIdx.x;
    const int w    = t >> 6;          // wave id 0..3
    const int lane = t & 63;
    const int ks   = w & 1;           // which half of each code tile-pair
    const int rowg = w >> 1;          // row group 0..1
    const int row  = blockIdx.x * ROWS_PER_BLOCK + rowg * 64 + lane;

    // x row -> registers
    float4 xr[16];
    const float4* xv = (const float4*)(X + (size_t)row * D);
#pragma unroll
    for (int p = 0; p < 16; ++p) xr[p] = xv[p];
    float r = 0.f;
#pragma unroll
    for (int p = 0; p < 16; ++p)
        r += xr[p].x * xr[p].x + xr[p].y * xr[p].y + xr[p].z * xr[p].z + xr[p].w * xr[p].w;

    float best = INFINITY;
    int bestk = 0;

    const int nIt = K / (KSPLIT * TK);   // 8
    for (int it = 0; it < nIt; ++it) {
        // cooperative stage: 2 contiguous tiles (8192 floats)
        const float4* src = (const float4*)(E + (size_t)it * (KSPLIT * TK * D));
        float4* dst = (float4*)sE;
#pragma unroll
        for (int p = 0; p < (KSPLIT * TK * D / 4) / THREADS; ++p)   // 8
            dst[p * THREADS + t] = src[p * THREADS + t];
        if (t < KSPLIT * TK) sC[t] = C[it * (KSPLIT * TK) + t];
        __syncthreads();

        const float* eb = sE + ks * TK * D;
        const float* cb = sC + ks * TK;
        const int kbase = it * (KSPLIT * TK) + ks * TK;

#pragma unroll 2
        for (int j = 0; j < TK; ++j) {
            const float4* ev = (const float4*)(eb + (size_t)j * D);
            float a0 = 0.f, a1 = 0.f, a2 = 0.f, a3 = 0.f;
#pragma unroll
            for (int p = 0; p < 16; p += 4) {
                float4 e0 = ev[p], e1 = ev[p + 1], e2 = ev[p + 2], e3 = ev[p + 3];
                a0 = fmaf(xr[p].x,     e0.x, a0); a0 = fmaf(xr[p].y,     e0.y, a0);
                a0 = fmaf(xr[p].z,     e0.z, a0); a0 = fmaf(xr[p].w,     e0.w, a0);
                a1 = fmaf(xr[p + 1].x, e1.x, a1); a1 = fmaf(xr[p + 1].y, e1.y, a1);
                a1 = fmaf(xr[p + 1].z, e1.z, a1); a1 = fmaf(xr[p + 1].w, e1.w, a1);
                a2 = fmaf(xr[p + 2].x, e2.x, a2); a2 = fmaf(xr[p + 2].y, e2.y, a2);
                a2 = fmaf(xr[p + 2].z, e2.z, a2); a2 = fmaf(xr[p + 2].w, e2.w, a2);
                a3 = fmaf(xr[p + 3].x, e3.x, a3); a3 = fmaf(xr[p + 3].y, e3.y, a3);
                a3 = fmaf(xr[p + 3].z, e3.z, a3); a3 = fmaf(xr[p + 3].w, e3.w, a3);
            }
            float dot = (a0 + a1) + (a2 + a3);
            // match numpy: (||x||^2 + ||e||^2) - 2*dot   (2*dot exact -> fmaf identical)
            float d = fmaf(-2.f, dot, r + cb[j]);
            if (d < best) { best = d; bestk = kbase + j; }
        }
        __syncthreads();
    }

    // combine the two k-halves of each row
    sD[t] = best; sI[t] = bestk;
    __syncthreads();
    float do_ = sD[t ^ 64];
    int   ko  = sI[t ^ 64];
    if (do_ < best || (do_ == best && ko < bestk)) { best = do_; bestk = ko; }

    // epilogue: each half-thread writes 32 of the row's 64 outputs
    const float4* q = (const float4*)(E + (size_t)bestk * D);
    float4* o = (float4*)(out + (size_t)row * D);
    float ls = 0.f;
#pragma unroll
    for (int p = 0; p < 8; ++p) {
        const int idx = ks * 8 + p;
        float4 qv = q[idx];
        o[idx] = qv;
        float dx = qv.x - xr[idx].x; ls = fmaf(dx, dx, ls);
        float dy = qv.y - xr[idx].y; ls = fmaf(dy, dy, ls);
        float dz = qv.z - xr[idx].z; ls = fmaf(dz, dz, ls);
        float dw = qv.w - xr[idx].w; ls = fmaf(dw, dw, ls);
    }
#pragma unroll
    for (int off = 32; off > 0; off >>= 1) ls += __shfl_down(ls, off, 64);
    if (lane == 0)
        atomicAdd(lossp, ls * (1.25f / ((float)NROWS * (float)D)));
}

extern "C" void kernel_launch(void* const* d_in, const int* in_sizes, int n_in,
                              void* d_out, int out_size, void* d_ws, size_t ws_size,
                              hipStream_t stream) {
    const float* X = (const float*)d_in[0];        // [64,1024,64] f32
    const float* E = (const float*)d_in[1];        // [1024,64] f32
    float* out = (float*)d_out;                    // N*D quantized + 1 loss
    float* C   = (float*)d_ws;                     // K norms

    // zero the loss accumulator slot (harness poisons d_out, no re-poison)
    hipMemsetAsync((char*)d_out + (size_t)NROWS * D * sizeof(float), 0,
                   sizeof(float), stream);

    vq_enorm<<<(K + 255) / 256, 256, 0, stream>>>(E, C);

    vq_main<<<NROWS / ROWS_PER_BLOCK, THREADS, 0, stream>>>(
        X, E, C, out, out + (size_t)NROWS * D);
}

// Round 2
// 133.445 us; speedup vs baseline: 2.3173x; 2.3173x over previous
//
#include <hip/hip_runtime.h>
#include <math.h>

#define NROWS 65536
#define D 64
#define K 1024
#define BR 128        // rows per block
#define BC 128        // codes per E tile
#define NT (K / BC)   // 8 tiles
#define THREADS 256

// c[k] = sum_j E[k][j]^2
__global__ void vq_enorm(const float* __restrict__ E, float* __restrict__ c) {
    int k = blockIdx.x * blockDim.x + threadIdx.x;
    if (k >= K) return;
    const float4* ev = (const float4*)(E + (size_t)k * D);
    float s = 0.f;
#pragma unroll
    for (int p = 0; p < D / 4; ++p) {
        float4 v = ev[p];
        s += v.x * v.x + v.y * v.y + v.z * v.z + v.w * v.w;
    }
    c[k] = s;
}

__global__ __launch_bounds__(THREADS, 2) void vq_main(
    const float* __restrict__ X, const float* __restrict__ E,
    const float* __restrict__ C, float* __restrict__ out,
    float* __restrict__ lossp)
{
    // float4-granular LDS tiles, XOR-swizzled on the chunk slot:
    // element (id, chunk c) lives at [id*16 + (c ^ ((id>>3)&15))]
    __shared__ float4 sX[BR * 16];   // 32 KB
    __shared__ float4 sE[BC * 16];   // 32 KB
    __shared__ float  sC[BC];
    __shared__ int    sIdx[BR];
    __shared__ float  sLoss[4];

    const int t  = threadIdx.x;
    const int tx = t & 15;          // code-group 0..15
    const int ty = t >> 4;          // row-group  0..15
    const int wv = t >> 6;

    const float4* Xg4 = (const float4*)X;
    const float4* Eg4 = (const float4*)E;

    // ---- stage X tile once (coalesced read, swizzled LDS write) ----
#pragma unroll
    for (int p = 0; p < 8; ++p) {
        int S = p * 256 + t;            // linear float4 slot in tile
        float4 v = Xg4[(size_t)blockIdx.x * BR * 16 + S];
        int id = S >> 4;                // row in tile
        int c  = S & 15;                // chunk
        sX[id * 16 + (c ^ ((id >> 3) & 15))] = v;
    }
    __syncthreads();

    // ---- per-thread row norms for its 8 rows ----
    float rr[8];
#pragma unroll
    for (int r = 0; r < 8; ++r) {
        float a = 0.f;
#pragma unroll
        for (int c = 0; c < 16; ++c) {
            float4 v = sX[(ty * 8 + r) * 16 + (c ^ ty)];
            a = fmaf(v.x, v.x, a); a = fmaf(v.y, v.y, a);
            a = fmaf(v.z, v.z, a); a = fmaf(v.w, v.w, a);
        }
        rr[r] = a;
    }

    float best[8]; int bk[8];
#pragma unroll
    for (int r = 0; r < 8; ++r) { best[r] = INFINITY; bk[r] = 0; }

    for (int kt = 0; kt < NT; ++kt) {
        __syncthreads();   // protect sE/sC from previous tile's readers
        // ---- stage E tile (coalesced read, swizzled LDS write) ----
#pragma unroll
        for (int p = 0; p < 8; ++p) {
            int S = p * 256 + t;
            float4 v = Eg4[(size_t)kt * BC * 16 + S];
            int id = S >> 4;
            int c  = S & 15;
            sE[id * 16 + (c ^ ((id >> 3) & 15))] = v;
        }
        if (t < BC) sC[t] = C[kt * BC + t];
        __syncthreads();

        // ---- 8x8 outer-product accumulation over D ----
        float acc[8][8];
#pragma unroll
        for (int r = 0; r < 8; ++r)
#pragma unroll
            for (int ci = 0; ci < 8; ++ci) acc[r][ci] = 0.f;

#pragma unroll 2
        for (int c = 0; c < 16; ++c) {
            float4 xa[8], eb[8];
#pragma unroll
            for (int i = 0; i < 8; ++i) xa[i] = sX[(ty * 8 + i) * 16 + (c ^ ty)];
#pragma unroll
            for (int i = 0; i < 8; ++i) eb[i] = sE[(tx * 8 + i) * 16 + (c ^ tx)];
#pragma unroll
            for (int r = 0; r < 8; ++r) {
#pragma unroll
                for (int ci = 0; ci < 8; ++ci) {
                    float a = acc[r][ci];
                    a = fmaf(xa[r].x, eb[ci].x, a);
                    a = fmaf(xa[r].y, eb[ci].y, a);
                    a = fmaf(xa[r].z, eb[ci].z, a);
                    a = fmaf(xa[r].w, eb[ci].w, a);
                    acc[r][ci] = a;
                }
            }
        }

        // ---- distances + per-row best (ascending code order per thread) ----
#pragma unroll
        for (int ci = 0; ci < 8; ++ci) {
            float cc = sC[tx * 8 + ci];
            int   kk = kt * BC + tx * 8 + ci;
#pragma unroll
            for (int r = 0; r < 8; ++r) {
                float dd = fmaf(-2.f, acc[r][ci], rr[r] + cc);
                if (dd < best[r]) { best[r] = dd; bk[r] = kk; }
            }
        }
    }

    // ---- argmin reduce across the 16 tx-lanes (tie -> smaller index) ----
#pragma unroll
    for (int r = 0; r < 8; ++r) {
        float b = best[r]; int k = bk[r];
#pragma unroll
        for (int off = 1; off < 16; off <<= 1) {
            float ob = __shfl_xor(b, off, 64);
            int   ok = __shfl_xor(k, off, 64);
            if (ob < b || (ob == b && ok < k)) { b = ob; k = ok; }
        }
        if (tx == 0) sIdx[ty * 8 + r] = k;
    }
    __syncthreads();

    // ---- gather quantized rows, write out, accumulate loss ----
    int row  = t >> 1;
    int half = t & 1;
    int kbest = sIdx[row];
    const float4* eq = Eg4 + (size_t)kbest * 16;
    float4* orow = (float4*)out + ((size_t)blockIdx.x * BR + row) * 16;
    int sw = (row >> 3) & 15;
    float ls = 0.f;
#pragma unroll
    for (int j = 0; j < 8; ++j) {
        int c = half * 8 + j;
        float4 q = eq[c];
        orow[c] = q;
        float4 xv = sX[row * 16 + (c ^ sw)];
        float dx = q.x - xv.x; ls = fmaf(dx, dx, ls);
        float dy = q.y - xv.y; ls = fmaf(dy, dy, ls);
        float dz = q.z - xv.z; ls = fmaf(dz, dz, ls);
        float dw = q.w - xv.w; ls = fmaf(dw, dw, ls);
    }
#pragma unroll
    for (int off = 32; off > 0; off >>= 1) ls += __shfl_down(ls, off, 64);
    if ((t & 63) == 0) sLoss[wv] = ls;
    __syncthreads();
    if (t == 0)
        atomicAdd(lossp, (sLoss[0] + sLoss[1] + sLoss[2] + sLoss[3]) *
                         (1.25f / ((float)NROWS * (float)D)));
}

extern "C" void kernel_launch(void* const* d_in, const int* in_sizes, int n_in,
                              void* d_out, int out_size, void* d_ws, size_t ws_size,
                              hipStream_t stream) {
    const float* X = (const float*)d_in[0];        // [64,1024,64] f32
    const float* E = (const float*)d_in[1];        // [1024,64] f32
    float* out = (float*)d_out;                    // N*D quantized + 1 loss
    float* C   = (float*)d_ws;                     // K code norms

    hipMemsetAsync((char*)d_out + (size_t)NROWS * D * sizeof(float), 0,
                   sizeof(float), stream);

    vq_enorm<<<(K + 255) / 256, 256, 0, stream>>>(E, C);

    vq_main<<<NROWS / BR, THREADS, 0, stream>>>(
        X, E, C, out, out + (size_t)NROWS * D);
}

// Round 3
// 132.726 us; speedup vs baseline: 2.3299x; 1.0054x over previous
//
#include <hip/hip_runtime.h>
#include <math.h>

#define NROWS 65536
#define D 64
#define K 1024
#define BR 128            // rows per block (4 waves x 32)
#define EC 128            // codes per staged chunk
#define NCH (K / EC)      // 8
#define THREADS 256
#define TAU 0.05f
#define LOSS_SCALE (1.25f / (65536.0f * 64.0f))

typedef short bf16x8 __attribute__((ext_vector_type(8)));
typedef float f32x4 __attribute__((ext_vector_type(4)));

__device__ inline unsigned short f2bf(float f) {
    unsigned int u = __float_as_uint(f);
    unsigned int r = u + 0x7fffu + ((u >> 16) & 1u);   // RN-even
    return (unsigned short)(r >> 16);
}
__device__ inline float bf2f(unsigned short h) {
    return __uint_as_float(((unsigned int)h) << 16);
}
__device__ inline void cvt8(const float4& a, const float4& b, bf16x8& h, bf16x8& l) {
    float f[8] = {a.x, a.y, a.z, a.w, b.x, b.y, b.z, b.w};
#pragma unroll
    for (int j = 0; j < 8; ++j) {
        unsigned short hb = f2bf(f[j]);
        h[j] = (short)hb;
        l[j] = (short)f2bf(f[j] - bf2f(hb));
    }
}

// c[k] = sum_j E[k][j]^2
__global__ void vq_enorm(const float* __restrict__ E, float* __restrict__ c) {
    int k = blockIdx.x * blockDim.x + threadIdx.x;
    if (k >= K) return;
    const float4* ev = (const float4*)(E + (size_t)k * D);
    float s = 0.f;
#pragma unroll
    for (int p = 0; p < D / 4; ++p) {
        float4 v = ev[p];
        s += v.x * v.x + v.y * v.y + v.z * v.z + v.w * v.w;
    }
    c[k] = s;
}

// split E into bf16 limbs
__global__ void vq_cvt(const float* __restrict__ E,
                       unsigned short* __restrict__ Ehi,
                       unsigned short* __restrict__ Elo) {
    int i = blockIdx.x * blockDim.x + threadIdx.x;   // 65536 elems
    float f = E[i];
    unsigned short h = f2bf(f);
    Ehi[i] = h;
    Elo[i] = f2bf(f - bf2f(h));
}

__global__ __launch_bounds__(THREADS, 2) void vq_main(
    const float* __restrict__ X, const float* __restrict__ E,
    const float* __restrict__ C,
    const unsigned short* __restrict__ Ehi, const unsigned short* __restrict__ Elo,
    int* __restrict__ bestk, int* __restrict__ flags, int* __restrict__ fcnt,
    float* __restrict__ out, float* __restrict__ lossp)
{
    __shared__ float4 sXf4[BR * 16];      // 32 KB, swizzled: [row*16 + (u ^ (row&15))]
    __shared__ bf16x8 sEh8[EC * 8];       // 16 KB, swizzled: [code*8 + (u8 ^ (code&7))]
    __shared__ bf16x8 sEl8[EC * 8];       // 16 KB
    __shared__ float  sCn[EC];
    __shared__ float  sRX[BR];
    __shared__ float  sRXp[THREADS];
    __shared__ int    sIdx[BR];

    const int t    = threadIdx.x;
    const int w    = t >> 6;
    const int lane = t & 63;
    const int l15  = lane & 15;
    const int l4   = lane >> 4;

    const float4* Xg4 = (const float4*)X;
    const float4* Eg4 = (const float4*)E;
    const bf16x8* Eh8 = (const bf16x8*)Ehi;
    const bf16x8* El8 = (const bf16x8*)Elo;

    // ---- stage X tile (f32, swizzled) ----
#pragma unroll
    for (int p = 0; p < 8; ++p) {
        int S = p * 256 + t;
        float4 v = Xg4[(size_t)blockIdx.x * (BR * 16) + S];
        int row = S >> 4, u = S & 15;
        sXf4[row * 16 + (u ^ (row & 15))] = v;
    }
    __syncthreads();

    // ---- row norms (2 threads per row) ----
    {
        int row = t >> 1, half = t & 1;
        float s = 0.f;
#pragma unroll
        for (int i = 0; i < 8; ++i) {
            int u = half * 8 + i;
            float4 v = sXf4[row * 16 + (u ^ (row & 15))];
            s = fmaf(v.x, v.x, s); s = fmaf(v.y, v.y, s);
            s = fmaf(v.z, v.z, s); s = fmaf(v.w, v.w, s);
        }
        sRXp[t] = s;
    }
    __syncthreads();
    if (t < BR) sRX[t] = sRXp[2 * t] + sRXp[2 * t + 1];
    __syncthreads();

    // ---- per-wave A fragments: rows w*32 + b*16 + (lane&15), k-octet lane>>4 ----
    bf16x8 ah[2][2], al[2][2];            // [rowblk][ktile]
#pragma unroll
    for (int b = 0; b < 2; ++b) {
        int lr = w * 32 + b * 16 + l15;
        int sw = lr & 15;
#pragma unroll
        for (int kt = 0; kt < 2; ++kt) {
            int u0 = kt * 8 + l4 * 2;
            float4 fa = sXf4[lr * 16 + (u0 ^ sw)];
            float4 fb = sXf4[lr * 16 + ((u0 + 1) ^ sw)];
            cvt8(fa, fb, ah[b][kt], al[b][kt]);
        }
    }
    float rxv[2][4];
#pragma unroll
    for (int b = 0; b < 2; ++b)
#pragma unroll
        for (int r = 0; r < 4; ++r)
            rxv[b][r] = sRX[w * 32 + b * 16 + l4 * 4 + r];

    float m[2][4], m2[2][4]; int bk[2][4];
#pragma unroll
    for (int b = 0; b < 2; ++b)
#pragma unroll
        for (int r = 0; r < 4; ++r) { m[b][r] = INFINITY; m2[b][r] = INFINITY; bk[b][r] = 0; }

    for (int ch = 0; ch < NCH; ++ch) {
        __syncthreads();
        // stage E limb chunk (pure swizzled copy)
#pragma unroll
        for (int p = 0; p < 4; ++p) {
            int S = p * 256 + t;                   // 1024 short8 units
            int code = S >> 3, u8 = S & 7;
            int di = code * 8 + (u8 ^ (code & 7));
            sEh8[di] = Eh8[(size_t)ch * (EC * 8) + S];
            sEl8[di] = El8[(size_t)ch * (EC * 8) + S];
        }
        if (t < EC) sCn[t] = C[ch * EC + t];
        __syncthreads();

#pragma unroll 2
        for (int tile = 0; tile < EC / 16; ++tile) {
            int tb = tile * 16;
            int code = tb + l15;
            int cs = code & 7;
            bf16x8 bh0 = sEh8[code * 8 + ((0 * 4 + l4) ^ cs)];
            bf16x8 bl0 = sEl8[code * 8 + ((0 * 4 + l4) ^ cs)];
            bf16x8 bh1 = sEh8[code * 8 + ((1 * 4 + l4) ^ cs)];
            bf16x8 bl1 = sEl8[code * 8 + ((1 * 4 + l4) ^ cs)];
            float ce = sCn[code];
            int kk = ch * EC + code;

            f32x4 acc[2];
#pragma unroll
            for (int b = 0; b < 2; ++b) {
                acc[b] = (f32x4){0.f, 0.f, 0.f, 0.f};
                acc[b] = __builtin_amdgcn_mfma_f32_16x16x32_bf16(ah[b][0], bh0, acc[b], 0, 0, 0);
                acc[b] = __builtin_amdgcn_mfma_f32_16x16x32_bf16(ah[b][0], bl0, acc[b], 0, 0, 0);
                acc[b] = __builtin_amdgcn_mfma_f32_16x16x32_bf16(al[b][0], bh0, acc[b], 0, 0, 0);
                acc[b] = __builtin_amdgcn_mfma_f32_16x16x32_bf16(ah[b][1], bh1, acc[b], 0, 0, 0);
                acc[b] = __builtin_amdgcn_mfma_f32_16x16x32_bf16(ah[b][1], bl1, acc[b], 0, 0, 0);
                acc[b] = __builtin_amdgcn_mfma_f32_16x16x32_bf16(al[b][1], bh1, acc[b], 0, 0, 0);
            }
#pragma unroll
            for (int b = 0; b < 2; ++b)
#pragma unroll
                for (int r = 0; r < 4; ++r) {
                    float dd = fmaf(-2.f, acc[b][r], rxv[b][r] + ce);
                    if (dd < m[b][r]) { m2[b][r] = m[b][r]; m[b][r] = dd; bk[b][r] = kk; }
                    else if (dd < m2[b][r]) m2[b][r] = dd;
                }
        }
    }

    // ---- per-row top2 reduce across the 16 col-lanes ----
#pragma unroll
    for (int b = 0; b < 2; ++b)
#pragma unroll
        for (int r = 0; r < 4; ++r) {
            float mm = m[b][r], mm2 = m2[b][r]; int kk = bk[b][r];
#pragma unroll
            for (int off = 1; off < 16; off <<= 1) {
                float om  = __shfl_xor(mm,  off, 64);
                float om2 = __shfl_xor(mm2, off, 64);
                int   ok  = __shfl_xor(kk,  off, 64);
                float mx = fmaxf(mm, om);
                mm2 = fminf(fminf(mm2, om2), mx);
                if (om < mm || (om == mm && ok < kk)) { mm = om; kk = ok; }
            }
            if (l15 == 0) {
                int lr = w * 32 + b * 16 + l4 * 4 + r;
                sIdx[lr] = kk;
                if (mm2 - mm < TAU) {
                    int pos = atomicAdd(fcnt, 1);
                    flags[pos] = blockIdx.x * BR + lr;
                }
            }
        }
    __syncthreads();

    // ---- provisional output + loss ----
    {
        int row = t >> 1, half = t & 1;
        int kb = sIdx[row];
        int grow = blockIdx.x * BR + row;
        if (half == 0) bestk[grow] = kb;
        const float4* eq = Eg4 + (size_t)kb * 16;
        float4* orow = (float4*)out + (size_t)grow * 16;
        int sw = row & 15;
        float ls = 0.f;
#pragma unroll
        for (int j = 0; j < 8; ++j) {
            int u = half * 8 + j;
            float4 q = eq[u];
            orow[u] = q;
            float4 xv = sXf4[row * 16 + (u ^ sw)];
            float dx = q.x - xv.x; ls = fmaf(dx, dx, ls);
            float dy = q.y - xv.y; ls = fmaf(dy, dy, ls);
            float dz = q.z - xv.z; ls = fmaf(dz, dz, ls);
            float dw = q.w - xv.w; ls = fmaf(dw, dw, ls);
        }
#pragma unroll
        for (int off = 32; off > 0; off >>= 1) ls += __shfl_down(ls, off, 64);
        if (lane == 0) atomicAdd(lossp, ls * LOSS_SCALE);
    }
}

// exact fp32 re-rank for ambiguous rows
__global__ __launch_bounds__(64) void vq_fix(
    const float* __restrict__ X, const float* __restrict__ E,
    const float* __restrict__ C,
    const int* __restrict__ bestk, const int* __restrict__ flags,
    const int* __restrict__ fcnt,
    float* __restrict__ out, float* __restrict__ lossp)
{
    __shared__ float4 sx4[16];
    const int lane = threadIdx.x;
    const float4* Eg4 = (const float4*)E;
    int nf = *fcnt;

    for (int i = blockIdx.x; i < nf; i += gridDim.x) {
        int row = flags[i];
        float xd = X[(size_t)row * D + lane];
        ((float*)sx4)[lane] = xd;
        float rx = xd * xd;
#pragma unroll
        for (int off = 1; off < 64; off <<= 1) rx += __shfl_xor(rx, off, 64);
        __syncthreads();

        float mm = INFINITY; int kb = 0;
        for (int jj = 0; jj < K / 64; ++jj) {
            int kk = jj * 64 + lane;
            const float4* er = Eg4 + (size_t)kk * 16;
            float a0 = 0.f, a1 = 0.f, a2 = 0.f, a3 = 0.f;
#pragma unroll
            for (int p = 0; p < 16; p += 4) {
                float4 xv0 = sx4[p],     e0 = er[p];
                float4 xv1 = sx4[p + 1], e1 = er[p + 1];
                float4 xv2 = sx4[p + 2], e2 = er[p + 2];
                float4 xv3 = sx4[p + 3], e3 = er[p + 3];
                a0 = fmaf(xv0.x, e0.x, a0); a0 = fmaf(xv0.y, e0.y, a0);
                a0 = fmaf(xv0.z, e0.z, a0); a0 = fmaf(xv0.w, e0.w, a0);
                a1 = fmaf(xv1.x, e1.x, a1); a1 = fmaf(xv1.y, e1.y, a1);
                a1 = fmaf(xv1.z, e1.z, a1); a1 = fmaf(xv1.w, e1.w, a1);
                a2 = fmaf(xv2.x, e2.x, a2); a2 = fmaf(xv2.y, e2.y, a2);
                a2 = fmaf(xv2.z, e2.z, a2); a2 = fmaf(xv2.w, e2.w, a2);
                a3 = fmaf(xv3.x, e3.x, a3); a3 = fmaf(xv3.y, e3.y, a3);
                a3 = fmaf(xv3.z, e3.z, a3); a3 = fmaf(xv3.w, e3.w, a3);
            }
            float dot = (a0 + a1) + (a2 + a3);
            float dd = fmaf(-2.f, dot, rx + C[kk]);
            if (dd < mm) { mm = dd; kb = kk; }
        }
#pragma unroll
        for (int off = 1; off < 64; off <<= 1) {
            float om = __shfl_xor(mm, off, 64);
            int   ok = __shfl_xor(kb, off, 64);
            if (om < mm || (om == mm && ok < kb)) { mm = om; kb = ok; }
        }
        int ko = bestk[row];
        if (kb != ko) {
            if (lane < 16) {
                float4 qn = Eg4[(size_t)kb * 16 + lane];
                float4 qo = Eg4[(size_t)ko * 16 + lane];
                float4 xv = sx4[lane];
                float dl = 0.f;
                float a, b2;
                a = qn.x - xv.x; b2 = qo.x - xv.x; dl += a * a - b2 * b2;
                a = qn.y - xv.y; b2 = qo.y - xv.y; dl += a * a - b2 * b2;
                a = qn.z - xv.z; b2 = qo.z - xv.z; dl += a * a - b2 * b2;
                a = qn.w - xv.w; b2 = qo.w - xv.w; dl += a * a - b2 * b2;
#pragma unroll
                for (int off = 1; off < 16; off <<= 1) dl += __shfl_xor(dl, off, 16);
                ((float4*)out)[(size_t)row * 16 + lane] = qn;
                if (lane == 0) atomicAdd(lossp, dl * LOSS_SCALE);
            }
        }
        __syncthreads();
    }
}

extern "C" void kernel_launch(void* const* d_in, const int* in_sizes, int n_in,
                              void* d_out, int out_size, void* d_ws, size_t ws_size,
                              hipStream_t stream) {
    const float* X = (const float*)d_in[0];        // [64,1024,64] f32
    const float* E = (const float*)d_in[1];        // [1024,64] f32
    float* out  = (float*)d_out;
    float* lossp = out + (size_t)NROWS * D;

    // ws layout (4-byte units)
    float* C      = (float*)d_ws;                               // 1024
    int*   bestk  = (int*)d_ws + 1024;                          // 65536
    int*   flags  = (int*)d_ws + 1024 + 65536;                  // 65536
    int*   fcnt   = (int*)d_ws + 1024 + 2 * 65536;              // 1 (+3 pad)
    unsigned short* Ehi = (unsigned short*)((int*)d_ws + 1024 + 2 * 65536 + 4);   // 64K ush
    unsigned short* Elo = Ehi + (size_t)K * D;

    hipMemsetAsync(lossp, 0, sizeof(float), stream);
    hipMemsetAsync(fcnt, 0, sizeof(int), stream);

    vq_enorm<<<(K + 255) / 256, 256, 0, stream>>>(E, C);
    vq_cvt<<<(K * D) / 256, 256, 0, stream>>>(E, Ehi, Elo);

    vq_main<<<NROWS / BR, THREADS, 0, stream>>>(
        X, E, C, Ehi, Elo, bestk, flags, fcnt, out, lossp);

    vq_fix<<<256, 64, 0, stream>>>(X, E, C, bestk, flags, fcnt, out, lossp);
}

// Round 4
// 72.264 us; speedup vs baseline: 4.2792x; 1.8367x over previous
//
#include <hip/hip_runtime.h>
#include <math.h>

#define NROWS 65536
#define D 64
#define K 1024
#define BR 64             // rows per block (4 waves x 16 rows)
#define EC 128            // codes per staged chunk
#define NCH (K / EC)      // 8
#define THREADS 256
#define TAU 0.02f
#define LOSS_SCALE (1.25f / (65536.0f * 64.0f))

typedef short bf16x8 __attribute__((ext_vector_type(8)));
typedef float f32x4 __attribute__((ext_vector_type(4)));

__device__ inline unsigned short f2bf(float f) {
    unsigned int u = __float_as_uint(f);
    unsigned int r = u + 0x7fffu + ((u >> 16) & 1u);   // RN-even
    return (unsigned short)(r >> 16);
}
__device__ inline float bf2f(unsigned short h) {
    return __uint_as_float(((unsigned int)h) << 16);
}
__device__ inline void cvt8(const float4& a, const float4& b, bf16x8& h, bf16x8& l) {
    float f[8] = {a.x, a.y, a.z, a.w, b.x, b.y, b.z, b.w};
#pragma unroll
    for (int j = 0; j < 8; ++j) {
        unsigned short hb = f2bf(f[j]);
        h[j] = (short)hb;
        l[j] = (short)f2bf(f[j] - bf2f(hb));
    }
}

// fused prep: code norms + bf16 limb split + zero loss/fcnt
__global__ void vq_prep(const float* __restrict__ E, float* __restrict__ C,
                        bf16x8* __restrict__ Eh8, bf16x8* __restrict__ El8,
                        float* __restrict__ lossp, int* __restrict__ fcnt) {
    int k = blockIdx.x * blockDim.x + threadIdx.x;
    if (k == 0) { *lossp = 0.f; *fcnt = 0; }
    if (k >= K) return;
    const float4* ev = (const float4*)(E + (size_t)k * D);
    float s = 0.f;
#pragma unroll
    for (int u = 0; u < 8; ++u) {
        float4 a = ev[2 * u], b = ev[2 * u + 1];
        s = fmaf(a.x, a.x, s); s = fmaf(a.y, a.y, s);
        s = fmaf(a.z, a.z, s); s = fmaf(a.w, a.w, s);
        s = fmaf(b.x, b.x, s); s = fmaf(b.y, b.y, s);
        s = fmaf(b.z, b.z, s); s = fmaf(b.w, b.w, s);
        bf16x8 h, l;
        cvt8(a, b, h, l);
        Eh8[(size_t)k * 8 + u] = h;
        El8[(size_t)k * 8 + u] = l;
    }
    C[k] = s;
}

__global__ __launch_bounds__(THREADS, 4) void vq_main(
    const float* __restrict__ X, const float* __restrict__ E,
    const float* __restrict__ C,
    const bf16x8* __restrict__ Eh8, const bf16x8* __restrict__ El8,
    int* __restrict__ bestk, int* __restrict__ flags, int* __restrict__ fcnt,
    float* __restrict__ out, float* __restrict__ lossp)
{
    __shared__ bf16x8 sEh8[EC * 8];   // 16 KB, swizzled [code*8 + (u8 ^ (code&7))]
    __shared__ bf16x8 sEl8[EC * 8];   // 16 KB
    __shared__ float  sCn[EC];
    __shared__ int    sIdx[BR];
    __shared__ float  sLoss[4];

    const int t    = threadIdx.x;
    const int w    = t >> 6;
    const int lane = t & 63;
    const int l15  = lane & 15;
    const int l4   = lane >> 4;

    const float4* Xg4 = (const float4*)X;

    // ---- A fragments straight from global (row = block*64 + w*16 + l15) ----
    size_t abase = ((size_t)blockIdx.x * BR + w * 16 + l15) * 16;   // float4 units
    bf16x8 ah[2], al[2];
    float nrm = 0.f;
#pragma unroll
    for (int kt = 0; kt < 2; ++kt) {
        float4 fa = Xg4[abase + kt * 8 + l4 * 2];
        float4 fb = Xg4[abase + kt * 8 + l4 * 2 + 1];
        nrm = fmaf(fa.x, fa.x, nrm); nrm = fmaf(fa.y, fa.y, nrm);
        nrm = fmaf(fa.z, fa.z, nrm); nrm = fmaf(fa.w, fa.w, nrm);
        nrm = fmaf(fb.x, fb.x, nrm); nrm = fmaf(fb.y, fb.y, nrm);
        nrm = fmaf(fb.z, fb.z, nrm); nrm = fmaf(fb.w, fb.w, nrm);
        cvt8(fa, fb, ah[kt], al[kt]);
    }
    // full row norm at every lane of its l15-group, then redistribute to C-layout rows
    nrm += __shfl_xor(nrm, 16, 64);
    nrm += __shfl_xor(nrm, 32, 64);
    float rxv[4];
#pragma unroll
    for (int r = 0; r < 4; ++r) rxv[r] = __shfl(nrm, l4 * 4 + r, 64);

    float m[4], m2[4]; int bk[4];
#pragma unroll
    for (int r = 0; r < 4; ++r) { m[r] = INFINITY; m2[r] = INFINITY; bk[r] = 0; }

    for (int ch = 0; ch < NCH; ++ch) {
        __syncthreads();
        // stage E limb chunk (coalesced read, swizzled LDS write)
#pragma unroll
        for (int p = 0; p < 4; ++p) {
            int S = p * 256 + t;
            int code = S >> 3, u8 = S & 7;
            int di = code * 8 + (u8 ^ (code & 7));
            sEh8[di] = Eh8[(size_t)ch * (EC * 8) + S];
            sEl8[di] = El8[(size_t)ch * (EC * 8) + S];
        }
        if (t < EC) sCn[t] = C[ch * EC + t];
        __syncthreads();

#pragma unroll 2
        for (int pr = 0; pr < 4; ++pr) {
            int c0 = pr * 32 + l15;
            int c1 = c0 + 16;
            int s0 = c0 & 7, s1 = c1 & 7;
            bf16x8 bh00 = sEh8[c0 * 8 + (l4 ^ s0)];
            bf16x8 bh01 = sEh8[c0 * 8 + ((4 + l4) ^ s0)];
            bf16x8 bl00 = sEl8[c0 * 8 + (l4 ^ s0)];
            bf16x8 bl01 = sEl8[c0 * 8 + ((4 + l4) ^ s0)];
            bf16x8 bh10 = sEh8[c1 * 8 + (l4 ^ s1)];
            bf16x8 bh11 = sEh8[c1 * 8 + ((4 + l4) ^ s1)];
            bf16x8 bl10 = sEl8[c1 * 8 + (l4 ^ s1)];
            bf16x8 bl11 = sEl8[c1 * 8 + ((4 + l4) ^ s1)];

            // 4 independent chains: hh (len 2) + cross (len 4), per tile
            f32x4 h0 = {0.f, 0.f, 0.f, 0.f}, x0 = {0.f, 0.f, 0.f, 0.f};
            f32x4 h1 = {0.f, 0.f, 0.f, 0.f}, x1 = {0.f, 0.f, 0.f, 0.f};
            h0 = __builtin_amdgcn_mfma_f32_16x16x32_bf16(ah[0], bh00, h0, 0, 0, 0);
            h1 = __builtin_amdgcn_mfma_f32_16x16x32_bf16(ah[0], bh10, h1, 0, 0, 0);
            x0 = __builtin_amdgcn_mfma_f32_16x16x32_bf16(al[0], bh00, x0, 0, 0, 0);
            x1 = __builtin_amdgcn_mfma_f32_16x16x32_bf16(al[0], bh10, x1, 0, 0, 0);
            h0 = __builtin_amdgcn_mfma_f32_16x16x32_bf16(ah[1], bh01, h0, 0, 0, 0);
            h1 = __builtin_amdgcn_mfma_f32_16x16x32_bf16(ah[1], bh11, h1, 0, 0, 0);
            x0 = __builtin_amdgcn_mfma_f32_16x16x32_bf16(ah[0], bl00, x0, 0, 0, 0);
            x1 = __builtin_amdgcn_mfma_f32_16x16x32_bf16(ah[0], bl10, x1, 0, 0, 0);
            x0 = __builtin_amdgcn_mfma_f32_16x16x32_bf16(al[1], bh01, x0, 0, 0, 0);
            x1 = __builtin_amdgcn_mfma_f32_16x16x32_bf16(al[1], bh11, x1, 0, 0, 0);
            x0 = __builtin_amdgcn_mfma_f32_16x16x32_bf16(ah[1], bl01, x0, 0, 0, 0);
            x1 = __builtin_amdgcn_mfma_f32_16x16x32_bf16(ah[1], bl11, x1, 0, 0, 0);

            float ce0 = sCn[pr * 32 + l15];
            float ce1 = sCn[pr * 32 + 16 + l15];
            int k0 = ch * EC + pr * 32 + l15;
            int k1 = k0 + 16;
#pragma unroll
            for (int r = 0; r < 4; ++r) {
                float d0 = fmaf(-2.f, h0[r] + x0[r], rxv[r] + ce0);
                m2[r] = fminf(m2[r], fmaxf(m[r], d0));
                bk[r] = (d0 < m[r]) ? k0 : bk[r];
                m[r]  = fminf(m[r], d0);
                float d1 = fmaf(-2.f, h1[r] + x1[r], rxv[r] + ce1);
                m2[r] = fminf(m2[r], fmaxf(m[r], d1));
                bk[r] = (d1 < m[r]) ? k1 : bk[r];
                m[r]  = fminf(m[r], d1);
            }
        }
    }

    // ---- per-row top2 reduce across the 16 col-lanes (tie -> lower index) ----
#pragma unroll
    for (int r = 0; r < 4; ++r) {
        float mm = m[r], mm2 = m2[r]; int kk = bk[r];
#pragma unroll
        for (int off = 1; off < 16; off <<= 1) {
            float om  = __shfl_xor(mm,  off, 64);
            float om2 = __shfl_xor(mm2, off, 64);
            int   ok  = __shfl_xor(kk,  off, 64);
            mm2 = fminf(fminf(mm2, om2), fmaxf(mm, om));
            if (om < mm || (om == mm && ok < kk)) { mm = om; kk = ok; }
        }
        if (l15 == 0) {
            int lr = w * 16 + l4 * 4 + r;
            sIdx[lr] = kk;
            if (mm2 - mm < TAU) {
                int pos = atomicAdd(fcnt, 1);
                flags[pos] = blockIdx.x * BR + lr;
            }
        }
    }
    __syncthreads();

    // ---- output gather + loss (4 threads per row) ----
    {
        int row = t >> 2, q = t & 3;
        int kb = sIdx[row];
        size_t grow = (size_t)blockIdx.x * BR + row;
        if (q == 0) bestk[grow] = kb;
        const float4* eq   = (const float4*)E + (size_t)kb * 16;
        const float4* xrow = Xg4 + grow * 16;
        float4* orow = (float4*)out + grow * 16;
        float ls = 0.f;
#pragma unroll
        for (int j = 0; j < 4; ++j) {
            int u = q * 4 + j;
            float4 qv = eq[u];
            float4 xv = xrow[u];
            orow[u] = qv;
            float dx = qv.x - xv.x; ls = fmaf(dx, dx, ls);
            float dy = qv.y - xv.y; ls = fmaf(dy, dy, ls);
            float dz = qv.z - xv.z; ls = fmaf(dz, dz, ls);
            float dw = qv.w - xv.w; ls = fmaf(dw, dw, ls);
        }
#pragma unroll
        for (int off = 32; off > 0; off >>= 1) ls += __shfl_down(ls, off, 64);
        if (lane == 0) sLoss[w] = ls;
        __syncthreads();
        if (t == 0)
            atomicAdd(lossp, (sLoss[0] + sLoss[1] + sLoss[2] + sLoss[3]) * LOSS_SCALE);
    }
}

// exact fp32 re-rank for ambiguous rows
__global__ __launch_bounds__(64) void vq_fix(
    const float* __restrict__ X, const float* __restrict__ E,
    const float* __restrict__ C,
    const int* __restrict__ bestk, const int* __restrict__ flags,
    const int* __restrict__ fcnt,
    float* __restrict__ out, float* __restrict__ lossp)
{
    __shared__ float4 sx4[16];
    const int lane = threadIdx.x;
    const float4* Eg4 = (const float4*)E;
    int nf = *fcnt;

    for (int i = blockIdx.x; i < nf; i += gridDim.x) {
        int row = flags[i];
        float xd = X[(size_t)row * D + lane];
        ((float*)sx4)[lane] = xd;
        float rx = xd * xd;
#pragma unroll
        for (int off = 1; off < 64; off <<= 1) rx += __shfl_xor(rx, off, 64);
        __syncthreads();

        float mm = INFINITY; int kb = 0;
        for (int jj = 0; jj < K / 64; ++jj) {
            int kk = jj * 64 + lane;
            const float4* er = Eg4 + (size_t)kk * 16;
            float a0 = 0.f, a1 = 0.f, a2 = 0.f, a3 = 0.f;
#pragma unroll
            for (int p = 0; p < 16; p += 4) {
                float4 xv0 = sx4[p],     e0 = er[p];
                float4 xv1 = sx4[p + 1], e1 = er[p + 1];
                float4 xv2 = sx4[p + 2], e2 = er[p + 2];
                float4 xv3 = sx4[p + 3], e3 = er[p + 3];
                a0 = fmaf(xv0.x, e0.x, a0); a0 = fmaf(xv0.y, e0.y, a0);
                a0 = fmaf(xv0.z, e0.z, a0); a0 = fmaf(xv0.w, e0.w, a0);
                a1 = fmaf(xv1.x, e1.x, a1); a1 = fmaf(xv1.y, e1.y, a1);
                a1 = fmaf(xv1.z, e1.z, a1); a1 = fmaf(xv1.w, e1.w, a1);
                a2 = fmaf(xv2.x, e2.x, a2); a2 = fmaf(xv2.y, e2.y, a2);
                a2 = fmaf(xv2.z, e2.z, a2); a2 = fmaf(xv2.w, e2.w, a2);
                a3 = fmaf(xv3.x, e3.x, a3); a3 = fmaf(xv3.y, e3.y, a3);
                a3 = fmaf(xv3.z, e3.z, a3); a3 = fmaf(xv3.w, e3.w, a3);
            }
            float dot = (a0 + a1) + (a2 + a3);
            float dd = fmaf(-2.f, dot, rx + C[kk]);
            if (dd < mm) { mm = dd; kb = kk; }
        }
#pragma unroll
        for (int off = 1; off < 64; off <<= 1) {
            float om = __shfl_xor(mm, off, 64);
            int   ok = __shfl_xor(kb, off, 64);
            if (om < mm || (om == mm && ok < kb)) { mm = om; kb = ok; }
        }
        int ko = bestk[row];
        if (kb != ko) {
            if (lane < 16) {
                float4 qn = Eg4[(size_t)kb * 16 + lane];
                float4 qo = Eg4[(size_t)ko * 16 + lane];
                float4 xv = sx4[lane];
                float dl = 0.f;
                float a, b2;
                a = qn.x - xv.x; b2 = qo.x - xv.x; dl += a * a - b2 * b2;
                a = qn.y - xv.y; b2 = qo.y - xv.y; dl += a * a - b2 * b2;
                a = qn.z - xv.z; b2 = qo.z - xv.z; dl += a * a - b2 * b2;
                a = qn.w - xv.w; b2 = qo.w - xv.w; dl += a * a - b2 * b2;
#pragma unroll
                for (int off = 1; off < 16; off <<= 1) dl += __shfl_xor(dl, off, 16);
                ((float4*)out)[(size_t)row * 16 + lane] = qn;
                if (lane == 0) atomicAdd(lossp, dl * LOSS_SCALE);
            }
        }
        __syncthreads();
    }
}

extern "C" void kernel_launch(void* const* d_in, const int* in_sizes, int n_in,
                              void* d_out, int out_size, void* d_ws, size_t ws_size,
                              hipStream_t stream) {
    const float* X = (const float*)d_in[0];        // [64,1024,64] f32
    const float* E = (const float*)d_in[1];        // [1024,64] f32
    float* out   = (float*)d_out;
    float* lossp = out + (size_t)NROWS * D;

    // ws layout (4-byte units)
    float* C     = (float*)d_ws;                               // 1024
    int*   bestk = (int*)d_ws + 1024;                          // 65536
    int*   flags = (int*)d_ws + 1024 + 65536;                  // 65536
    int*   fcnt  = (int*)d_ws + 1024 + 2 * 65536;              // 1 (+3 pad)
    bf16x8* Eh8  = (bf16x8*)((int*)d_ws + 1024 + 2 * 65536 + 4);   // K*8 units
    bf16x8* El8  = Eh8 + (size_t)K * 8;

    vq_prep<<<(K + 255) / 256, 256, 0, stream>>>(E, C, Eh8, El8, lossp, fcnt);

    vq_main<<<NROWS / BR, THREADS, 0, stream>>>(
        X, E, C, Eh8, El8, bestk, flags, fcnt, out, lossp);

    vq_fix<<<1024, 64, 0, stream>>>(X, E, C, bestk, flags, fcnt, out, lossp);
}

// Round 5
// 71.549 us; speedup vs baseline: 4.3220x; 1.0100x over previous
//
#include <hip/hip_runtime.h>
#include <math.h>

#define NROWS 65536
#define D 64
#define K 1024
#define BR 128            // rows per block = 4 waves x 32 rows
#define EC 128            // codes per staged chunk
#define NCH (K / EC)      // 8
#define THREADS 256
#define TAU_S 0.005f      // gap threshold in s-units (dist gap = 2x)
#define LOSS_SCALE (1.25f / (65536.0f * 64.0f))

typedef short bf16x8 __attribute__((ext_vector_type(8)));
typedef float f32x4 __attribute__((ext_vector_type(4)));

__device__ inline unsigned short f2bf(float f) {
    unsigned int u = __float_as_uint(f);
    unsigned int r = u + 0x7fffu + ((u >> 16) & 1u);   // RN-even
    return (unsigned short)(r >> 16);
}
__device__ inline float bf2f(unsigned short h) {
    return __uint_as_float(((unsigned int)h) << 16);
}
__device__ inline void cvt8(const float4& a, const float4& b, bf16x8& h, bf16x8& l) {
    float f[8] = {a.x, a.y, a.z, a.w, b.x, b.y, b.z, b.w};
#pragma unroll
    for (int j = 0; j < 8; ++j) {
        unsigned short hb = f2bf(f[j]);
        h[j] = (short)hb;
        l[j] = (short)f2bf(f[j] - bf2f(hb));
    }
}

// prep: exact code norms C, half-norms Ch=0.5*C, bf16 limb split, zero loss/fcnt
__global__ void vq_prep(const float* __restrict__ E, float* __restrict__ C,
                        float* __restrict__ Ch,
                        bf16x8* __restrict__ Eh8, bf16x8* __restrict__ El8,
                        float* __restrict__ lossp, int* __restrict__ fcnt) {
    int k = blockIdx.x * blockDim.x + threadIdx.x;
    if (k == 0) { *lossp = 0.f; *fcnt = 0; }
    if (k >= K) return;
    const float4* ev = (const float4*)(E + (size_t)k * D);
    float s = 0.f;
#pragma unroll
    for (int u = 0; u < 8; ++u) {
        float4 a = ev[2 * u], b = ev[2 * u + 1];
        s = fmaf(a.x, a.x, s); s = fmaf(a.y, a.y, s);
        s = fmaf(a.z, a.z, s); s = fmaf(a.w, a.w, s);
        s = fmaf(b.x, b.x, s); s = fmaf(b.y, b.y, s);
        s = fmaf(b.z, b.z, s); s = fmaf(b.w, b.w, s);
        bf16x8 h, l;
        cvt8(a, b, h, l);
        Eh8[(size_t)k * 8 + u] = h;
        El8[(size_t)k * 8 + u] = l;
    }
    C[k] = s;
    Ch[k] = 0.5f * s;
}

__global__ __launch_bounds__(THREADS, 2) void vq_main(
    const float* __restrict__ X, const float* __restrict__ E,
    const float* __restrict__ Ch,
    const bf16x8* __restrict__ Eh8, const bf16x8* __restrict__ El8,
    int* __restrict__ bestk, int* __restrict__ flags, int* __restrict__ fcnt,
    float* __restrict__ out, float* __restrict__ lossp)
{
    __shared__ bf16x8 sEh8[EC * 8];   // 16 KB, swizzled [code*8 + (u8 ^ (code&7))]
    __shared__ bf16x8 sEl8[EC * 8];   // 16 KB
    __shared__ float  sCn[EC];
    __shared__ int    sIdx[BR];
    __shared__ float  sLoss[4];

    const int t    = threadIdx.x;
    const int w    = t >> 6;
    const int lane = t & 63;
    const int l15  = lane & 15;
    const int l4   = lane >> 4;

    const float4* Xg4 = (const float4*)X;

    // ---- A fragments for 2 row-tiles (32 rows per wave), straight from global ----
    bf16x8 ah[2][2], al[2][2];
#pragma unroll
    for (int rt = 0; rt < 2; ++rt) {
        size_t abase = ((size_t)blockIdx.x * BR + w * 32 + rt * 16 + l15) * 16;
#pragma unroll
        for (int kt = 0; kt < 2; ++kt) {
            float4 fa = Xg4[abase + kt * 8 + l4 * 2];
            float4 fb = Xg4[abase + kt * 8 + l4 * 2 + 1];
            cvt8(fa, fb, ah[rt][kt], al[rt][kt]);
        }
    }

    // running argmax of s = dot - 0.5*||e||^2  (row-norm cancels in ranking & gap)
    float m[2][4], m2[2][4]; int bk[2][4];
#pragma unroll
    for (int rt = 0; rt < 2; ++rt)
#pragma unroll
        for (int r = 0; r < 4; ++r) { m[rt][r] = -INFINITY; m2[rt][r] = -INFINITY; bk[rt][r] = 0; }

    // ---- reg-staged double buffer ----
    bf16x8 rh[4], rl[4];
    float creg = 0.f;
#pragma unroll
    for (int p = 0; p < 4; ++p) {
        int S = p * 256 + t;
        rh[p] = Eh8[S];
        rl[p] = El8[S];
    }
    if (t < EC) creg = Ch[t];
#pragma unroll
    for (int p = 0; p < 4; ++p) {
        int S = p * 256 + t;
        int code = S >> 3, u8 = S & 7;
        int di = code * 8 + (u8 ^ (code & 7));
        sEh8[di] = rh[p];
        sEl8[di] = rl[p];
    }
    if (t < EC) sCn[t] = creg;
    __syncthreads();

    for (int ch = 0; ch < NCH; ++ch) {
        if (ch + 1 < NCH) {
#pragma unroll
            for (int p = 0; p < 4; ++p) {
                int S = p * 256 + t;
                rh[p] = Eh8[(size_t)(ch + 1) * (EC * 8) + S];
                rl[p] = El8[(size_t)(ch + 1) * (EC * 8) + S];
            }
            if (t < EC) creg = Ch[(ch + 1) * EC + t];
        }

#pragma unroll 2
        for (int t8 = 0; t8 < 8; ++t8) {
            int code = t8 * 16 + l15;
            int cs = code & 7;
            bf16x8 bh0 = sEh8[code * 8 + (l4 ^ cs)];
            bf16x8 bh1 = sEh8[code * 8 + ((4 + l4) ^ cs)];
            bf16x8 bl0 = sEl8[code * 8 + (l4 ^ cs)];
            bf16x8 bl1 = sEl8[code * 8 + ((4 + l4) ^ cs)];
            float ce2 = sCn[code];
            int kk = ch * EC + code;

#pragma unroll
            for (int rt = 0; rt < 2; ++rt) {
                f32x4 h = {0.f, 0.f, 0.f, 0.f}, x = {0.f, 0.f, 0.f, 0.f};
                h = __builtin_amdgcn_mfma_f32_16x16x32_bf16(ah[rt][0], bh0, h, 0, 0, 0);
                x = __builtin_amdgcn_mfma_f32_16x16x32_bf16(al[rt][0], bh0, x, 0, 0, 0);
                h = __builtin_amdgcn_mfma_f32_16x16x32_bf16(ah[rt][1], bh1, h, 0, 0, 0);
                x = __builtin_amdgcn_mfma_f32_16x16x32_bf16(al[rt][1], bh1, x, 0, 0, 0);
                x = __builtin_amdgcn_mfma_f32_16x16x32_bf16(ah[rt][0], bl0, x, 0, 0, 0);
                x = __builtin_amdgcn_mfma_f32_16x16x32_bf16(ah[rt][1], bl1, x, 0, 0, 0);
#pragma unroll
                for (int r = 0; r < 4; ++r) {
                    float v = (h[r] + x[r]) - ce2;
                    m2[rt][r] = fmaxf(m2[rt][r], fminf(m[rt][r], v));
                    bk[rt][r] = (v > m[rt][r]) ? kk : bk[rt][r];
                    m[rt][r]  = fmaxf(m[rt][r], v);
                }
            }
        }
        __syncthreads();
        if (ch + 1 < NCH) {
#pragma unroll
            for (int p = 0; p < 4; ++p) {
                int S = p * 256 + t;
                int code = S >> 3, u8 = S & 7;
                int di = code * 8 + (u8 ^ (code & 7));
                sEh8[di] = rh[p];
                sEl8[di] = rl[p];
            }
            if (t < EC) sCn[t] = creg;
        }
        __syncthreads();
    }

    // ---- per-row top2 reduce across the 16 col-lanes (argmax s, tie -> lower k) ----
#pragma unroll
    for (int rt = 0; rt < 2; ++rt)
#pragma unroll
        for (int r = 0; r < 4; ++r) {
            float mm = m[rt][r], mm2 = m2[rt][r]; int kk = bk[rt][r];
#pragma unroll
            for (int off = 1; off < 16; off <<= 1) {
                float om  = __shfl_xor(mm,  off, 64);
                float om2 = __shfl_xor(mm2, off, 64);
                int   ok  = __shfl_xor(kk,  off, 64);
                mm2 = fmaxf(fmaxf(mm2, om2), fminf(mm, om));
                if (om > mm || (om == mm && ok < kk)) { mm = om; kk = ok; }
            }
            if (l15 == 0) {
                int lr = w * 32 + rt * 16 + l4 * 4 + r;
                sIdx[lr] = kk;
                if (mm - mm2 < TAU_S) {
                    int pos = atomicAdd(fcnt, 1);
                    flags[pos] = blockIdx.x * BR + lr;
                }
            }
        }
    __syncthreads();

    // ---- output gather + loss (2 threads per row) ----
    {
        int row = t >> 1, half = t & 1;
        int kb = sIdx[row];
        size_t grow = (size_t)blockIdx.x * BR + row;
        if (half == 0) bestk[grow] = kb;
        const float4* eq   = (const float4*)E + (size_t)kb * 16;
        const float4* xrow = Xg4 + grow * 16;
        float4* orow = (float4*)out + grow * 16;
        float ls = 0.f;
#pragma unroll
        for (int j = 0; j < 8; ++j) {
            int u = half * 8 + j;
            float4 qv = eq[u];
            float4 xv = xrow[u];
            orow[u] = qv;
            float dx = qv.x - xv.x; ls = fmaf(dx, dx, ls);
            float dy = qv.y - xv.y; ls = fmaf(dy, dy, ls);
            float dz = qv.z - xv.z; ls = fmaf(dz, dz, ls);
            float dw = qv.w - xv.w; ls = fmaf(dw, dw, ls);
        }
#pragma unroll
        for (int off = 32; off > 0; off >>= 1) ls += __shfl_down(ls, off, 64);
        if (lane == 0) sLoss[w] = ls;
        __syncthreads();
        if (t == 0)
            atomicAdd(lossp, (sLoss[0] + sLoss[1] + sLoss[2] + sLoss[3]) * LOSS_SCALE);
    }
}

// exact fp32 re-rank for ambiguous rows
__global__ __launch_bounds__(64) void vq_fix(
    const float* __restrict__ X, const float* __restrict__ E,
    const float* __restrict__ C,
    const int* __restrict__ bestk, const int* __restrict__ flags,
    const int* __restrict__ fcnt,
    float* __restrict__ out, float* __restrict__ lossp)
{
    __shared__ float4 sx4[16];
    const int lane = threadIdx.x;
    const float4* Eg4 = (const float4*)E;
    int nf = *fcnt;

    for (int i = blockIdx.x; i < nf; i += gridDim.x) {
        int row = flags[i];
        float xd = X[(size_t)row * D + lane];
        ((float*)sx4)[lane] = xd;
        float rx = xd * xd;
#pragma unroll
        for (int off = 1; off < 64; off <<= 1) rx += __shfl_xor(rx, off, 64);
        __syncthreads();

        float mm = INFINITY; int kb = 0;
        for (int jj = 0; jj < K / 64; ++jj) {
            int kk = jj * 64 + lane;
            const float4* er = Eg4 + (size_t)kk * 16;
            float a0 = 0.f, a1 = 0.f, a2 = 0.f, a3 = 0.f;
#pragma unroll
            for (int p = 0; p < 16; p += 4) {
                float4 xv0 = sx4[p],     e0 = er[p];
                float4 xv1 = sx4[p + 1], e1 = er[p + 1];
                float4 xv2 = sx4[p + 2], e2 = er[p + 2];
                float4 xv3 = sx4[p + 3], e3 = er[p + 3];
                a0 = fmaf(xv0.x, e0.x, a0); a0 = fmaf(xv0.y, e0.y, a0);
                a0 = fmaf(xv0.z, e0.z, a0); a0 = fmaf(xv0.w, e0.w, a0);
                a1 = fmaf(xv1.x, e1.x, a1); a1 = fmaf(xv1.y, e1.y, a1);
                a1 = fmaf(xv1.z, e1.z, a1); a1 = fmaf(xv1.w, e1.w, a1);
                a2 = fmaf(xv2.x, e2.x, a2); a2 = fmaf(xv2.y, e2.y, a2);
                a2 = fmaf(xv2.z, e2.z, a2); a2 = fmaf(xv2.w, e2.w, a2);
                a3 = fmaf(xv3.x, e3.x, a3); a3 = fmaf(xv3.y, e3.y, a3);
                a3 = fmaf(xv3.z, e3.z, a3); a3 = fmaf(xv3.w, e3.w, a3);
            }
            float dot = (a0 + a1) + (a2 + a3);
            float dd = fmaf(-2.f, dot, rx + C[kk]);
            if (dd < mm) { mm = dd; kb = kk; }
        }
#pragma unroll
        for (int off = 1; off < 64; off <<= 1) {
            float om = __shfl_xor(mm, off, 64);
            int   ok = __shfl_xor(kb, off, 64);
            if (om < mm || (om == mm && ok < kb)) { mm = om; kb = ok; }
        }
        int ko = bestk[row];
        if (kb != ko) {
            if (lane < 16) {
                float4 qn = Eg4[(size_t)kb * 16 + lane];
                float4 qo = Eg4[(size_t)ko * 16 + lane];
                float4 xv = sx4[lane];
                float dl = 0.f;
                float a, b2;
                a = qn.x - xv.x; b2 = qo.x - xv.x; dl += a * a - b2 * b2;
                a = qn.y - xv.y; b2 = qo.y - xv.y; dl += a * a - b2 * b2;
                a = qn.z - xv.z; b2 = qo.z - xv.z; dl += a * a - b2 * b2;
                a = qn.w - xv.w; b2 = qo.w - xv.w; dl += a * a - b2 * b2;
#pragma unroll
                for (int off = 1; off < 16; off <<= 1) dl += __shfl_xor(dl, off, 16);
                ((float4*)out)[(size_t)row * 16 + lane] = qn;
                if (lane == 0) atomicAdd(lossp, dl * LOSS_SCALE);
            }
        }
        __syncthreads();
    }
}

extern "C" void kernel_launch(void* const* d_in, const int* in_sizes, int n_in,
                              void* d_out, int out_size, void* d_ws, size_t ws_size,
                              hipStream_t stream) {
    const float* X = (const float*)d_in[0];        // [64,1024,64] f32
    const float* E = (const float*)d_in[1];        // [1024,64] f32
    float* out   = (float*)d_out;
    float* lossp = out + (size_t)NROWS * D;

    // ws layout (4-byte units)
    float* C     = (float*)d_ws;                                 // 1024
    float* Ch    = (float*)d_ws + 1024;                          // 1024
    int*   bestk = (int*)d_ws + 2048;                            // 65536
    int*   flags = (int*)d_ws + 2048 + 65536;                    // 65536
    int*   fcnt  = (int*)d_ws + 2048 + 2 * 65536;                // 1 (+3 pad)
    bf16x8* Eh8  = (bf16x8*)((int*)d_ws + 2048 + 2 * 65536 + 4); // K*8 units
    bf16x8* El8  = Eh8 + (size_t)K * 8;

    vq_prep<<<(K + 255) / 256, 256, 0, stream>>>(E, C, Ch, Eh8, El8, lossp, fcnt);

    vq_main<<<NROWS / BR, THREADS, 0, stream>>>(
        X, E, Ch, Eh8, El8, bestk, flags, fcnt, out, lossp);

    vq_fix<<<512, 64, 0, stream>>>(X, E, C, bestk, flags, fcnt, out, lossp);
}